// Round 1
// baseline (1484.958 us; speedup 1.0000x reference)
//
#include <hip/hip_runtime.h>
#include <math.h>

#define NB 2
#define CD 512
#define C8D 64
#define NSP 4096

// ---------------- xc = alpha*x1 + beta*x2 ----------------
__global__ __launch_bounds__(256) void k_combine(
    const float* __restrict__ x1, const float* __restrict__ x2,
    const float* __restrict__ alpha, const float* __restrict__ beta,
    float* __restrict__ xc, int n4)
{
    float a = alpha[0], b = beta[0];
    int i = blockIdx.x * blockDim.x + threadIdx.x;
    int stride = gridDim.x * blockDim.x;
    const float4* x1v = (const float4*)x1;
    const float4* x2v = (const float4*)x2;
    float4* xcv = (float4*)xc;
    for (int j = i; j < n4; j += stride) {
        float4 u = x1v[j], v = x2v[j];
        xcv[j] = make_float4(a*u.x + b*v.x, a*u.y + b*v.y, a*u.z + b*v.z, a*u.w + b*v.w);
    }
}

// ---------------- proj GEMM: out[o][n] = sum_c W[o][c] x[c][n] + bias[o]*scale ----------------
// TRANS==1 writes out[n][o] (used for f, so apply-GEMM loads are coalesced over c)
template<int TRANS>
__global__ __launch_bounds__(256) void k_proj(
    const float* __restrict__ W, const float* __restrict__ bias,
    const float* __restrict__ x, float* __restrict__ out, int O,
    const float* __restrict__ sA, const float* __restrict__ sB)
{
    __shared__ float Wt[16][64];  // [k][o]
    __shared__ float Xt[16][64];  // [k][n]
    int t = threadIdx.x;
    int n0 = blockIdx.x * 64, o0 = blockIdx.y * 64, b = blockIdx.z;
    const float* xb = x + (size_t)b * CD * NSP;
    float acc[4][4] = {};
    int i = t >> 4, j = t & 15;
    for (int k0 = 0; k0 < CD; k0 += 16) {
        int ol = t >> 2, k4 = (t & 3) << 2;
        float4 wv = *(const float4*)&W[(size_t)(o0 + ol) * CD + k0 + k4];
        int kl = t >> 4, n4i = (t & 15) << 2;
        float4 xv = *(const float4*)&xb[(size_t)(k0 + kl) * NSP + n0 + n4i];
        __syncthreads();
        Wt[k4 + 0][ol] = wv.x; Wt[k4 + 1][ol] = wv.y;
        Wt[k4 + 2][ol] = wv.z; Wt[k4 + 3][ol] = wv.w;
        *(float4*)&Xt[kl][n4i] = xv;
        __syncthreads();
        #pragma unroll
        for (int kk = 0; kk < 16; kk++) {
            float4 a4 = *(const float4*)&Wt[kk][i << 2];
            float4 b4 = *(const float4*)&Xt[kk][j << 2];
            acc[0][0] += a4.x*b4.x; acc[0][1] += a4.x*b4.y; acc[0][2] += a4.x*b4.z; acc[0][3] += a4.x*b4.w;
            acc[1][0] += a4.y*b4.x; acc[1][1] += a4.y*b4.y; acc[1][2] += a4.y*b4.z; acc[1][3] += a4.y*b4.w;
            acc[2][0] += a4.z*b4.x; acc[2][1] += a4.z*b4.y; acc[2][2] += a4.z*b4.z; acc[2][3] += a4.z*b4.w;
            acc[3][0] += a4.w*b4.x; acc[3][1] += a4.w*b4.y; acc[3][2] += a4.w*b4.z; acc[3][3] += a4.w*b4.w;
        }
    }
    float scale = (sA ? sA[0] : 1.0f) + (sB ? sB[0] : 0.0f);
    #pragma unroll
    for (int oi = 0; oi < 4; oi++) {
        int o = o0 + (i << 2) + oi;
        float bv = bias[o] * scale;
        if (TRANS) {
            float* ob = out + (size_t)b * NSP * CD;
            #pragma unroll
            for (int nj = 0; nj < 4; nj++)
                ob[(size_t)(n0 + (j << 2) + nj) * CD + o] = acc[oi][nj] + bv;
        } else {
            float* ob = out + (size_t)b * O * NSP;
            float4 r = make_float4(acc[oi][0] + bv, acc[oi][1] + bv, acc[oi][2] + bv, acc[oi][3] + bv);
            *(float4*)&ob[(size_t)o * NSP + n0 + (j << 2)] = r;
        }
    }
}

// ---------------- fused attention-diff apply ----------------
// Per block: 16 query rows n. Phase 1: online max/logsumexp of S12[n,:], S21[n,:].
// Phase 2: recompute S tiles, P = |softmax12 - softmax21| in LDS, O += P @ f^T.
__global__ __launch_bounds__(256) void k_fused(
    const float* __restrict__ a1, const float* __restrict__ b1,
    const float* __restrict__ a2, const float* __restrict__ b2,
    const float* __restrict__ ft, float* __restrict__ out)
{
    __shared__ float a1t[64][16];
    __shared__ float a2t[64][16];
    __shared__ float P[1152];   // phase2: [16][64]; epilogue: [64][17]
    int t = threadIdx.x;
    int n0 = blockIdx.x * 16, b = blockIdx.y;
    const float* a1g = a1 + (size_t)b * C8D * NSP;
    const float* b1g = b1 + (size_t)b * C8D * NSP;
    const float* a2g = a2 + (size_t)b * C8D * NSP;
    const float* b2g = b2 + (size_t)b * C8D * NSP;
    {
        int c = t >> 2, q = t & 3;
        *(float4*)&a1t[c][q << 2] = *(const float4*)&a1g[(size_t)c * NSP + n0 + (q << 2)];
        *(float4*)&a2t[c][q << 2] = *(const float4*)&a2g[(size_t)c * NSP + n0 + (q << 2)];
    }
    __syncthreads();
    int lane = t & 63, w = t >> 6;
    int rbase = w << 2;   // wave-private rows: rbase..rbase+3

    // ---- phase 1: stats ----
    float mx12[4], sm12[4], mx21[4], sm21[4];
    #pragma unroll
    for (int r = 0; r < 4; r++) { mx12[r] = -1e30f; sm12[r] = 0.f; mx21[r] = -1e30f; sm21[r] = 0.f; }
    for (int mc = 0; mc < NSP; mc += 64) {
        int m = mc + lane;
        float s12[4] = {0.f,0.f,0.f,0.f}, s21[4] = {0.f,0.f,0.f,0.f};
        #pragma unroll 4
        for (int c = 0; c < 64; c++) {
            float bv2 = b2g[(size_t)c * NSP + m];
            float bv1 = b1g[(size_t)c * NSP + m];
            float4 av1 = *(const float4*)&a1t[c][rbase];
            float4 av2 = *(const float4*)&a2t[c][rbase];
            s12[0] += av1.x*bv2; s12[1] += av1.y*bv2; s12[2] += av1.z*bv2; s12[3] += av1.w*bv2;
            s21[0] += av2.x*bv1; s21[1] += av2.y*bv1; s21[2] += av2.z*bv1; s21[3] += av2.w*bv1;
        }
        #pragma unroll
        for (int r = 0; r < 4; r++) {
            float nm = fmaxf(mx12[r], s12[r]);
            sm12[r] = sm12[r]*__expf(mx12[r]-nm) + __expf(s12[r]-nm);
            mx12[r] = nm;
            nm = fmaxf(mx21[r], s21[r]);
            sm21[r] = sm21[r]*__expf(mx21[r]-nm) + __expf(s21[r]-nm);
            mx21[r] = nm;
        }
    }
    #pragma unroll
    for (int r = 0; r < 4; r++) {
        #pragma unroll
        for (int off = 32; off > 0; off >>= 1) {
            float om = __shfl_xor(mx12[r], off);
            float ol = __shfl_xor(sm12[r], off);
            float nm = fmaxf(mx12[r], om);
            sm12[r] = sm12[r]*__expf(mx12[r]-nm) + ol*__expf(om-nm);
            mx12[r] = nm;
            om = __shfl_xor(mx21[r], off);
            ol = __shfl_xor(sm21[r], off);
            nm = fmaxf(mx21[r], om);
            sm21[r] = sm21[r]*__expf(mx21[r]-nm) + ol*__expf(om-nm);
            mx21[r] = nm;
        }
    }
    float ls12[4], ls21[4];
    #pragma unroll
    for (int r = 0; r < 4; r++) {
        ls12[r] = mx12[r] + __logf(sm12[r]);
        ls21[r] = mx21[r] + __logf(sm21[r]);
    }

    // ---- phase 2: recompute S, P = |p12-p21|, O += P @ f^T ----
    const float* ftb = ft + (size_t)b * NSP * CD;
    float acc[4][8] = {};
    int cl = lane;
    for (int mc = 0; mc < NSP; mc += 64) {
        int m = mc + lane;
        float s12[4] = {0.f,0.f,0.f,0.f}, s21[4] = {0.f,0.f,0.f,0.f};
        #pragma unroll 4
        for (int c = 0; c < 64; c++) {
            float bv2 = b2g[(size_t)c * NSP + m];
            float bv1 = b1g[(size_t)c * NSP + m];
            float4 av1 = *(const float4*)&a1t[c][rbase];
            float4 av2 = *(const float4*)&a2t[c][rbase];
            s12[0] += av1.x*bv2; s12[1] += av1.y*bv2; s12[2] += av1.z*bv2; s12[3] += av1.w*bv2;
            s21[0] += av2.x*bv1; s21[1] += av2.y*bv1; s21[2] += av2.z*bv1; s21[3] += av2.w*bv1;
        }
        #pragma unroll
        for (int r = 0; r < 4; r++) {
            float p12 = __expf(s12[r] - ls12[r]);
            float p21 = __expf(s21[r] - ls21[r]);
            P[(rbase + r) * 64 + lane] = fabsf(p12 - p21);
        }
        __syncthreads();
        for (int mm4 = 0; mm4 < 16; mm4++) {
            float p4[4][4];
            #pragma unroll
            for (int i2 = 0; i2 < 4; i2++) {
                float4 pv = *(const float4*)&P[(rbase + i2) * 64 + (mm4 << 2)];
                p4[i2][0] = pv.x; p4[i2][1] = pv.y; p4[i2][2] = pv.z; p4[i2][3] = pv.w;
            }
            #pragma unroll
            for (int q = 0; q < 4; q++) {
                const float* fr = &ftb[(size_t)(mc + (mm4 << 2) + q) * CD];
                float4 f0 = *(const float4*)&fr[cl << 2];
                float4 f1 = *(const float4*)&fr[256 + (cl << 2)];
                #pragma unroll
                for (int i2 = 0; i2 < 4; i2++) {
                    float pv = p4[i2][q];
                    acc[i2][0] += pv*f0.x; acc[i2][1] += pv*f0.y;
                    acc[i2][2] += pv*f0.z; acc[i2][3] += pv*f0.w;
                    acc[i2][4] += pv*f1.x; acc[i2][5] += pv*f1.y;
                    acc[i2][6] += pv*f1.z; acc[i2][7] += pv*f1.w;
                }
            }
        }
        __syncthreads();
    }

    // ---- epilogue: LDS transpose so global stores are coalesced over n ----
    float* ob = out + (size_t)b * CD * NSP;
    #pragma unroll
    for (int jj = 0; jj < 8; jj++) {
        __syncthreads();
        #pragma unroll
        for (int i2 = 0; i2 < 4; i2++)
            P[cl * 17 + rbase + i2] = acc[i2][jj];
        __syncthreads();
        int r = t >> 2, seg = t & 3;
        int c = (jj < 4) ? ((r << 2) + jj) : (256 + (r << 2) + jj - 4);
        float4 v;
        v.x = P[r * 17 + (seg << 2) + 0];
        v.y = P[r * 17 + (seg << 2) + 1];
        v.z = P[r * 17 + (seg << 2) + 2];
        v.w = P[r * 17 + (seg << 2) + 3];
        *(float4*)&ob[(size_t)c * NSP + n0 + (seg << 2)] = v;
    }
}

extern "C" void kernel_launch(void* const* d_in, const int* in_sizes, int n_in,
                              void* d_out, int out_size, void* d_ws, size_t ws_size,
                              hipStream_t stream)
{
    const float* x1 = (const float*)d_in[0];
    const float* x2 = (const float*)d_in[1];
    const float* Wb = (const float*)d_in[2];
    const float* bb = (const float*)d_in[3];
    const float* Wc = (const float*)d_in[4];
    const float* bc = (const float*)d_in[5];
    const float* Wd = (const float*)d_in[6];
    const float* bd = (const float*)d_in[7];
    const float* alpha = (const float*)d_in[8];
    const float* beta  = (const float*)d_in[9];
    float* out = (float*)d_out;
    float* ws = (float*)d_ws;

    // workspace layout (floats): a1,b1,a2,b2: 4 x 524288 ; ft: 4194304  => ~25.2 MB
    float* a1 = ws;
    float* b1 = ws + 524288;
    float* a2 = ws + 1048576;
    float* b2 = ws + 1572864;
    float* ft = ws + 2097152;
    float* xc = out;  // reuse output buffer as scratch for alpha*x1+beta*x2

    k_combine<<<2048, 256, 0, stream>>>(x1, x2, alpha, beta, xc, NB * CD * NSP / 4);

    dim3 gsmall(NSP / 64, 1, NB);
    k_proj<0><<<gsmall, 256, 0, stream>>>(Wb, bb, x1, a1, C8D, nullptr, nullptr);
    k_proj<0><<<gsmall, 256, 0, stream>>>(Wc, bc, x1, b1, C8D, nullptr, nullptr);
    k_proj<0><<<gsmall, 256, 0, stream>>>(Wb, bb, x2, a2, C8D, nullptr, nullptr);
    k_proj<0><<<gsmall, 256, 0, stream>>>(Wc, bc, x2, b2, C8D, nullptr, nullptr);

    dim3 gf(NSP / 64, CD / 64, NB);
    k_proj<1><<<gf, 256, 0, stream>>>(Wd, bd, xc, ft, CD, alpha, beta);

    dim3 ga(NSP / 16, NB);
    k_fused<<<ga, 256, 0, stream>>>(a1, b1, a2, b2, ft, out);
}

// Round 2
// 464.871 us; speedup vs baseline: 3.1943x; 3.1943x over previous
//
#include <hip/hip_runtime.h>
#include <math.h>

#define NB 2
#define CD 512
#define NSP 4096
#define LOG2E 1.44269504088896f
#define SHIFT 20.0f

typedef unsigned short u16;
typedef __attribute__((ext_vector_type(8))) short short8;
typedef __attribute__((ext_vector_type(4))) float f32x4;

__device__ __forceinline__ u16 f2bf(float f) {
    union { float f; unsigned u; } v; v.f = f;
    unsigned r = (v.u + 0x7fffu + ((v.u >> 16) & 1u)) >> 16;
    return (u16)r;
}
__device__ __forceinline__ float fexp2(float x) {
#if __has_builtin(__builtin_amdgcn_exp2f)
    return __builtin_amdgcn_exp2f(x);
#else
    return exp2f(x);
#endif
}
__device__ __forceinline__ float flog2(float x) {
#if __has_builtin(__builtin_amdgcn_logf)
    return __builtin_amdgcn_logf(x);
#else
    return log2f(x);
#endif
}

// ---------------- xc = alpha*x1 + beta*x2 ----------------
__global__ __launch_bounds__(256) void k_combine(
    const float* __restrict__ x1, const float* __restrict__ x2,
    const float* __restrict__ alpha, const float* __restrict__ beta,
    float* __restrict__ xc, int n4)
{
    float a = alpha[0], b = beta[0];
    int i = blockIdx.x * blockDim.x + threadIdx.x;
    int stride = gridDim.x * blockDim.x;
    const float4* x1v = (const float4*)x1;
    const float4* x2v = (const float4*)x2;
    float4* xcv = (float4*)xc;
    for (int j = i; j < n4; j += stride) {
        float4 u = x1v[j], v = x2v[j];
        xcv[j] = make_float4(a*u.x + b*v.x, a*u.y + b*v.y, a*u.z + b*v.z, a*u.w + b*v.w);
    }
}

// ---------------- small projections: a = conv_b(x) (scaled by log2e), b = conv_c(x) ----------------
// outputs bf16 in [n][64] layout (pos-major, channel contiguous: MFMA-frag friendly)
__global__ __launch_bounds__(256) void k_projAB(
    const float* __restrict__ Wb, const float* __restrict__ bbias,
    const float* __restrict__ Wc, const float* __restrict__ cbias,
    const float* __restrict__ x1, const float* __restrict__ x2,
    u16* __restrict__ a1, u16* __restrict__ b1,
    u16* __restrict__ a2, u16* __restrict__ b2)
{
    __shared__ float WtB[16][64];
    __shared__ float WtC[16][64];
    __shared__ float Xt[16][64];
    int t = threadIdx.x;
    int n0 = blockIdx.x * 64, b = blockIdx.y, which = blockIdx.z;
    const float* xb = (which ? x2 : x1) + (size_t)b * CD * NSP;
    u16* oA = (which ? a2 : a1) + (size_t)b * NSP * 64;
    u16* oB = (which ? b2 : b1) + (size_t)b * NSP * 64;
    float accA[4][4] = {}, accB[4][4] = {};
    int i = t >> 4, j = t & 15;
    for (int k0 = 0; k0 < CD; k0 += 16) {
        int ol = t >> 2, k4 = (t & 3) << 2;
        float4 wb = *(const float4*)&Wb[(size_t)ol * CD + k0 + k4];
        float4 wc = *(const float4*)&Wc[(size_t)ol * CD + k0 + k4];
        int kl = t >> 4, n4i = (t & 15) << 2;
        float4 xv = *(const float4*)&xb[(size_t)(k0 + kl) * NSP + n0 + n4i];
        __syncthreads();
        WtB[k4 + 0][ol] = wb.x; WtB[k4 + 1][ol] = wb.y;
        WtB[k4 + 2][ol] = wb.z; WtB[k4 + 3][ol] = wb.w;
        WtC[k4 + 0][ol] = wc.x; WtC[k4 + 1][ol] = wc.y;
        WtC[k4 + 2][ol] = wc.z; WtC[k4 + 3][ol] = wc.w;
        *(float4*)&Xt[kl][n4i] = xv;
        __syncthreads();
        #pragma unroll
        for (int kk = 0; kk < 16; kk++) {
            float4 a4 = *(const float4*)&WtB[kk][i << 2];
            float4 c4 = *(const float4*)&WtC[kk][i << 2];
            float4 b4 = *(const float4*)&Xt[kk][j << 2];
            accA[0][0] += a4.x*b4.x; accA[0][1] += a4.x*b4.y; accA[0][2] += a4.x*b4.z; accA[0][3] += a4.x*b4.w;
            accA[1][0] += a4.y*b4.x; accA[1][1] += a4.y*b4.y; accA[1][2] += a4.y*b4.z; accA[1][3] += a4.y*b4.w;
            accA[2][0] += a4.z*b4.x; accA[2][1] += a4.z*b4.y; accA[2][2] += a4.z*b4.z; accA[2][3] += a4.z*b4.w;
            accA[3][0] += a4.w*b4.x; accA[3][1] += a4.w*b4.y; accA[3][2] += a4.w*b4.z; accA[3][3] += a4.w*b4.w;
            accB[0][0] += c4.x*b4.x; accB[0][1] += c4.x*b4.y; accB[0][2] += c4.x*b4.z; accB[0][3] += c4.x*b4.w;
            accB[1][0] += c4.y*b4.x; accB[1][1] += c4.y*b4.y; accB[1][2] += c4.y*b4.z; accB[1][3] += c4.y*b4.w;
            accB[2][0] += c4.z*b4.x; accB[2][1] += c4.z*b4.y; accB[2][2] += c4.z*b4.z; accB[2][3] += c4.z*b4.w;
            accB[3][0] += c4.w*b4.x; accB[3][1] += c4.w*b4.y; accB[3][2] += c4.w*b4.z; accB[3][3] += c4.w*b4.w;
        }
    }
    #pragma unroll
    for (int oi = 0; oi < 4; oi++) {
        int o = (i << 2) + oi;
        float ba = bbias[o], bc_ = cbias[o];
        #pragma unroll
        for (int nj = 0; nj < 4; nj++) {
            size_t n = n0 + (j << 2) + nj;
            oA[n * 64 + o] = f2bf((accA[oi][nj] + ba) * LOG2E);
            oB[n * 64 + o] = f2bf(accB[oi][nj] + bc_);
        }
    }
}

// ---------------- ft = conv_d(xc), bf16 out in natural [c][m] layout ----------------
__global__ __launch_bounds__(256) void k_projD(
    const float* __restrict__ W, const float* __restrict__ bias,
    const float* __restrict__ x, u16* __restrict__ out,
    const float* __restrict__ alpha, const float* __restrict__ beta)
{
    __shared__ float Wt[16][64];
    __shared__ float Xt[16][64];
    int t = threadIdx.x;
    int n0 = blockIdx.x * 64, o0 = blockIdx.y * 64, b = blockIdx.z;
    const float* xb = x + (size_t)b * CD * NSP;
    float acc[4][4] = {};
    int i = t >> 4, j = t & 15;
    for (int k0 = 0; k0 < CD; k0 += 16) {
        int ol = t >> 2, k4 = (t & 3) << 2;
        float4 wv = *(const float4*)&W[(size_t)(o0 + ol) * CD + k0 + k4];
        int kl = t >> 4, n4i = (t & 15) << 2;
        float4 xv = *(const float4*)&xb[(size_t)(k0 + kl) * NSP + n0 + n4i];
        __syncthreads();
        Wt[k4 + 0][ol] = wv.x; Wt[k4 + 1][ol] = wv.y;
        Wt[k4 + 2][ol] = wv.z; Wt[k4 + 3][ol] = wv.w;
        *(float4*)&Xt[kl][n4i] = xv;
        __syncthreads();
        #pragma unroll
        for (int kk = 0; kk < 16; kk++) {
            float4 a4 = *(const float4*)&Wt[kk][i << 2];
            float4 b4 = *(const float4*)&Xt[kk][j << 2];
            acc[0][0] += a4.x*b4.x; acc[0][1] += a4.x*b4.y; acc[0][2] += a4.x*b4.z; acc[0][3] += a4.x*b4.w;
            acc[1][0] += a4.y*b4.x; acc[1][1] += a4.y*b4.y; acc[1][2] += a4.y*b4.z; acc[1][3] += a4.y*b4.w;
            acc[2][0] += a4.z*b4.x; acc[2][1] += a4.z*b4.y; acc[2][2] += a4.z*b4.z; acc[2][3] += a4.z*b4.w;
            acc[3][0] += a4.w*b4.x; acc[3][1] += a4.w*b4.y; acc[3][2] += a4.w*b4.z; acc[3][3] += a4.w*b4.w;
        }
    }
    float scale = alpha[0] + beta[0];
    u16* ob = out + (size_t)b * CD * NSP;
    #pragma unroll
    for (int oi = 0; oi < 4; oi++) {
        int o = o0 + (i << 2) + oi;
        float bv = bias[o] * scale;
        unsigned p0 = (unsigned)f2bf(acc[oi][0] + bv) | ((unsigned)f2bf(acc[oi][1] + bv) << 16);
        unsigned p1 = (unsigned)f2bf(acc[oi][2] + bv) | ((unsigned)f2bf(acc[oi][3] + bv) << 16);
        *(uint2*)&ob[(size_t)o * NSP + n0 + (j << 2)] = make_uint2(p0, p1);
    }
}

// ---------------- fused attention-diff apply (MFMA bf16) ----------------
// block = 4 waves, 32 query rows. Phase1: row sum of exp2(s-SHIFT) via MFMA.
// Phase2: recompute S, P=|p12-p21| bf16 in LDS, O += P @ ft^T via MFMA.
__global__ __launch_bounds__(256) void k_fused2(
    const u16* __restrict__ a1, const u16* __restrict__ b1,
    const u16* __restrict__ a2, const u16* __restrict__ b2,
    const u16* __restrict__ ft, float* __restrict__ out)
{
    __shared__ u16 a1t[32][72], a2t[32][72];
    __shared__ u16 b1t[128][72], b2t[128][72];
    __shared__ u16 Pt[32][136];
    __shared__ float stats[2][4][32];
    __shared__ float lsArr[2][32];

    int t = threadIdx.x;
    int lane = t & 63, w = t >> 6, q = lane >> 4, l15 = lane & 15;
    int blk = blockIdx.x;
    int xcd = blk & 7, slot = blk >> 3;
    int batch = xcd & 1;                       // segregate batches by XCD for L2 locality
    int n0 = ((xcd >> 1) * 32 + slot) * 32;

    const u16* a1g = a1 + ((size_t)batch * NSP + n0) * 64;
    const u16* a2g = a2 + ((size_t)batch * NSP + n0) * 64;
    const u16* b1g = b1 + (size_t)batch * NSP * 64;
    const u16* b2g = b2 + (size_t)batch * NSP * 64;
    const u16* ftb = ft + (size_t)batch * CD * NSP;

    // stage a-tiles (contiguous 4 KB each)
    {
        uint4 va = ((const uint4*)a1g)[t];
        uint4 vb = ((const uint4*)a2g)[t];
        *(uint4*)&a1t[t >> 3][(t & 7) * 8] = va;
        *(uint4*)&a2t[t >> 3][(t & 7) * 8] = vb;
    }
    __syncthreads();

    // loop-invariant A fragments
    short8 a1f[2][2], a2f[2][2];
    #pragma unroll
    for (int i = 0; i < 2; i++)
        #pragma unroll
        for (int k = 0; k < 2; k++) {
            a1f[i][k] = *(const short8*)&a1t[i*16 + l15][k*32 + q*8];
            a2f[i][k] = *(const short8*)&a2t[i*16 + l15][k*32 + q*8];
        }

    // ---- phase 1: denominators ----
    float sm[2][2][4];
    #pragma unroll
    for (int m = 0; m < 2; m++)
        #pragma unroll
        for (int i = 0; i < 2; i++)
            #pragma unroll
            for (int r = 0; r < 4; r++) sm[m][i][r] = 0.f;

    for (int mc = 0; mc < NSP; mc += 128) {
        __syncthreads();
        const uint4* s1 = (const uint4*)(b1g + (size_t)mc * 64);
        const uint4* s2 = (const uint4*)(b2g + (size_t)mc * 64);
        #pragma unroll
        for (int kk = 0; kk < 4; kk++) {
            int row = t >> 1, col = (t & 1) * 32 + kk * 8;
            *(uint4*)&b1t[row][col] = s1[t*4 + kk];
            *(uint4*)&b2t[row][col] = s2[t*4 + kk];
        }
        __syncthreads();
        #pragma unroll
        for (int mt = 0; mt < 2; mt++) {
            int ml = w*32 + mt*16 + l15;
            short8 f1k0 = *(const short8*)&b1t[ml][q*8];
            short8 f1k1 = *(const short8*)&b1t[ml][32 + q*8];
            short8 f2k0 = *(const short8*)&b2t[ml][q*8];
            short8 f2k1 = *(const short8*)&b2t[ml][32 + q*8];
            #pragma unroll
            for (int i = 0; i < 2; i++) {
                f32x4 z = {0.f, 0.f, 0.f, 0.f};
                f32x4 s12 = __builtin_amdgcn_mfma_f32_16x16x32_bf16(a1f[i][0], f2k0, z, 0, 0, 0);
                s12 = __builtin_amdgcn_mfma_f32_16x16x32_bf16(a1f[i][1], f2k1, s12, 0, 0, 0);
                f32x4 s21 = __builtin_amdgcn_mfma_f32_16x16x32_bf16(a2f[i][0], f1k0, z, 0, 0, 0);
                s21 = __builtin_amdgcn_mfma_f32_16x16x32_bf16(a2f[i][1], f1k1, s21, 0, 0, 0);
                #pragma unroll
                for (int r = 0; r < 4; r++) {
                    sm[0][i][r] += fexp2(s12[r] - SHIFT);
                    sm[1][i][r] += fexp2(s21[r] - SHIFT);
                }
            }
        }
    }
    // reduce: butterfly across the 16-lane group, then across waves via LDS
    #pragma unroll
    for (int m = 0; m < 2; m++)
        #pragma unroll
        for (int i = 0; i < 2; i++)
            #pragma unroll
            for (int r = 0; r < 4; r++) {
                float v = sm[m][i][r];
                v += __shfl_xor(v, 1); v += __shfl_xor(v, 2);
                v += __shfl_xor(v, 4); v += __shfl_xor(v, 8);
                if (l15 == 0) stats[m][w][i*16 + q*4 + r] = v;
            }
    __syncthreads();
    if (t < 64) {
        int m = t >> 5, row = t & 31;
        float s = stats[m][0][row] + stats[m][1][row] + stats[m][2][row] + stats[m][3][row];
        lsArr[m][row] = SHIFT + flog2(s);
    }
    __syncthreads();
    float ls12[2][4], ls21[2][4];
    #pragma unroll
    for (int i = 0; i < 2; i++)
        #pragma unroll
        for (int r = 0; r < 4; r++) {
            ls12[i][r] = lsArr[0][i*16 + q*4 + r];
            ls21[i][r] = lsArr[1][i*16 + q*4 + r];
        }

    // ---- phase 2: recompute S, P, apply ----
    f32x4 o[2][8];
    #pragma unroll
    for (int i = 0; i < 2; i++)
        #pragma unroll
        for (int j = 0; j < 8; j++) { f32x4 z = {0.f,0.f,0.f,0.f}; o[i][j] = z; }

    for (int mc = 0; mc < NSP; mc += 128) {
        __syncthreads();
        const uint4* s1 = (const uint4*)(b1g + (size_t)mc * 64);
        const uint4* s2 = (const uint4*)(b2g + (size_t)mc * 64);
        #pragma unroll
        for (int kk = 0; kk < 4; kk++) {
            int row = t >> 1, col = (t & 1) * 32 + kk * 8;
            *(uint4*)&b1t[row][col] = s1[t*4 + kk];
            *(uint4*)&b2t[row][col] = s2[t*4 + kk];
        }
        __syncthreads();
        #pragma unroll
        for (int mt = 0; mt < 2; mt++) {
            int ml = w*32 + mt*16 + l15;
            short8 f1k0 = *(const short8*)&b1t[ml][q*8];
            short8 f1k1 = *(const short8*)&b1t[ml][32 + q*8];
            short8 f2k0 = *(const short8*)&b2t[ml][q*8];
            short8 f2k1 = *(const short8*)&b2t[ml][32 + q*8];
            #pragma unroll
            for (int i = 0; i < 2; i++) {
                f32x4 z = {0.f, 0.f, 0.f, 0.f};
                f32x4 s12 = __builtin_amdgcn_mfma_f32_16x16x32_bf16(a1f[i][0], f2k0, z, 0, 0, 0);
                s12 = __builtin_amdgcn_mfma_f32_16x16x32_bf16(a1f[i][1], f2k1, s12, 0, 0, 0);
                f32x4 s21 = __builtin_amdgcn_mfma_f32_16x16x32_bf16(a2f[i][0], f1k0, z, 0, 0, 0);
                s21 = __builtin_amdgcn_mfma_f32_16x16x32_bf16(a2f[i][1], f1k1, s21, 0, 0, 0);
                #pragma unroll
                for (int r = 0; r < 4; r++) {
                    float p12 = fexp2(s12[r] - ls12[i][r]);
                    float p21 = fexp2(s21[r] - ls21[i][r]);
                    Pt[i*16 + q*4 + r][w*32 + mt*16 + l15] = f2bf(fabsf(p12 - p21));
                }
            }
        }
        __syncthreads();
        short8 pa[2][4];
        #pragma unroll
        for (int i = 0; i < 2; i++)
            #pragma unroll
            for (int k = 0; k < 4; k++)
                pa[i][k] = *(const short8*)&Pt[i*16 + l15][k*32 + q*8];
        #pragma unroll
        for (int j = 0; j < 8; j++) {
            const u16* fr = ftb + (size_t)(w*128 + j*16 + l15) * NSP + mc;
            short8 fb0 = *(const short8*)(fr + q*8);
            short8 fb1 = *(const short8*)(fr + 32 + q*8);
            short8 fb2 = *(const short8*)(fr + 64 + q*8);
            short8 fb3 = *(const short8*)(fr + 96 + q*8);
            #pragma unroll
            for (int i = 0; i < 2; i++) {
                o[i][j] = __builtin_amdgcn_mfma_f32_16x16x32_bf16(pa[i][0], fb0, o[i][j], 0, 0, 0);
                o[i][j] = __builtin_amdgcn_mfma_f32_16x16x32_bf16(pa[i][1], fb1, o[i][j], 0, 0, 0);
                o[i][j] = __builtin_amdgcn_mfma_f32_16x16x32_bf16(pa[i][2], fb2, o[i][j], 0, 0, 0);
                o[i][j] = __builtin_amdgcn_mfma_f32_16x16x32_bf16(pa[i][3], fb3, o[i][j], 0, 0, 0);
            }
        }
    }

    // epilogue: C-layout rows are 4 consecutive n -> one float4 store per tile
    float* ob = out + (size_t)batch * CD * NSP;
    #pragma unroll
    for (int i = 0; i < 2; i++)
        #pragma unroll
        for (int j = 0; j < 8; j++) {
            int c = w*128 + j*16 + l15;
            *(f32x4*)&ob[(size_t)c * NSP + n0 + i*16 + q*4] = o[i][j];
        }
}

extern "C" void kernel_launch(void* const* d_in, const int* in_sizes, int n_in,
                              void* d_out, int out_size, void* d_ws, size_t ws_size,
                              hipStream_t stream)
{
    const float* x1 = (const float*)d_in[0];
    const float* x2 = (const float*)d_in[1];
    const float* Wb = (const float*)d_in[2];
    const float* bb = (const float*)d_in[3];
    const float* Wc = (const float*)d_in[4];
    const float* bc = (const float*)d_in[5];
    const float* Wd = (const float*)d_in[6];
    const float* bd = (const float*)d_in[7];
    const float* alpha = (const float*)d_in[8];
    const float* beta  = (const float*)d_in[9];
    float* out = (float*)d_out;

    // ws layout (u16): a1,b1,a2,b2: 4 x 524288 ; ft: 4194304  => ~12.6 MB
    u16* ws = (u16*)d_ws;
    u16* a1 = ws;
    u16* b1 = ws + 524288;
    u16* a2 = ws + 1048576;
    u16* b2 = ws + 1572864;
    u16* ft = ws + 2097152;
    float* xc = out;  // reuse output buffer as scratch for alpha*x1+beta*x2

    k_combine<<<2048, 256, 0, stream>>>(x1, x2, alpha, beta, xc, NB * CD * NSP / 4);

    dim3 gab(NSP / 64, NB, 2);
    k_projAB<<<gab, 256, 0, stream>>>(Wb, bb, Wc, bc, x1, x2, a1, b1, a2, b2);

    dim3 gf(NSP / 64, CD / 64, NB);
    k_projD<<<gf, 256, 0, stream>>>(Wd, bd, xc, ft, alpha, beta);

    k_fused2<<<256, 256, 0, stream>>>(a1, b1, a2, b2, ft, out);
}

// Round 3
// 325.173 us; speedup vs baseline: 4.5667x; 1.4296x over previous
//
#include <hip/hip_runtime.h>
#include <math.h>

#define NB 2
#define CDIM 512
#define NT 4096
#define LOG2E 1.44269504088896f
#define SHIFT 20.0f

typedef unsigned short u16;
typedef __attribute__((ext_vector_type(8))) short short8;
typedef __attribute__((ext_vector_type(4))) float f32x4;

union U8 { u16 v[8]; uint4 u4; };
union U4 { u16 v[4]; uint2 u2; };

__device__ __forceinline__ u16 f2bf(float f) {
    union { float f; unsigned u; } v; v.f = f;
    unsigned r = (v.u + 0x7fffu + ((v.u >> 16) & 1u)) >> 16;
    return (u16)r;
}
__device__ __forceinline__ float bf2f(u16 b) {
    union { float f; unsigned u; } v; v.u = ((unsigned)b) << 16; return v.f;
}
__device__ __forceinline__ float fexp2(float x) {
#if __has_builtin(__builtin_amdgcn_exp2f)
    return __builtin_amdgcn_exp2f(x);
#else
    return exp2f(x);
#endif
}
__device__ __forceinline__ float flog2(float x) {
#if __has_builtin(__builtin_amdgcn_logf)
    return __builtin_amdgcn_logf(x);
#else
    return log2f(x);
#endif
}

// ---------------- weight convert: W1=[Wb*log2e; Wc; alpha*Wd] bf16, W2f=beta*Wd bf16 ----------------
__global__ __launch_bounds__(256) void k_convW(
    const float* __restrict__ Wb, const float* __restrict__ Wc, const float* __restrict__ Wd,
    const float* __restrict__ alpha, const float* __restrict__ beta,
    u16* __restrict__ W1, u16* __restrict__ W2f)
{
    int r = blockIdx.x, t = threadIdx.x;
    const float* src; float scale; u16* dst;
    if (r < 640) {
        dst = W1 + (size_t)r * CDIM;
        if (r < 64)       { src = Wb + (size_t)r * CDIM;        scale = LOG2E; }
        else if (r < 128) { src = Wc + (size_t)(r - 64) * CDIM; scale = 1.f; }
        else              { src = Wd + (size_t)(r - 128) * CDIM; scale = alpha[0]; }
    } else {
        int rr = r - 640;
        dst = W2f + (size_t)rr * CDIM;
        src = Wd + (size_t)rr * CDIM;
        scale = beta[0];
    }
    float2 v = *(const float2*)&src[t * 2];
    unsigned p = (unsigned)f2bf(v.x * scale) | ((unsigned)f2bf(v.y * scale) << 16);
    *(unsigned*)&dst[t * 2] = p;
}

// ---------------- x [b][c][n] fp32 -> xT [b][n][c] bf16 (64x64 tiles via LDS) ----------------
__global__ __launch_bounds__(256) void k_prep(
    const float* __restrict__ x1, const float* __restrict__ x2,
    u16* __restrict__ x1T, u16* __restrict__ x2T)
{
    __shared__ float Lt[64][65];
    int t = threadIdx.x;
    int c0 = blockIdx.x * 64, n0 = blockIdx.y * 64;
    int which = blockIdx.z & 1, batch = blockIdx.z >> 1;
    const float* src = (which ? x2 : x1) + (size_t)batch * CDIM * NT;
    u16* dst = (which ? x2T : x1T) + (size_t)batch * NT * CDIM;
    #pragma unroll
    for (int p = 0; p < 4; p++) {
        int cr = p * 16 + (t >> 4), nc = (t & 15) * 4;
        float4 v = *(const float4*)&src[(size_t)(c0 + cr) * NT + n0 + nc];
        Lt[cr][nc] = v.x; Lt[cr][nc + 1] = v.y; Lt[cr][nc + 2] = v.z; Lt[cr][nc + 3] = v.w;
    }
    __syncthreads();
    #pragma unroll
    for (int p = 0; p < 2; p++) {
        int nr = p * 32 + (t >> 3), cc = (t & 7) * 8;
        U8 u;
        #pragma unroll
        for (int j = 0; j < 8; j++) u.v[j] = f2bf(Lt[cc + j][nr]);
        *(uint4*)&dst[(size_t)(n0 + nr) * CDIM + c0 + cc] = u.u4;
    }
}

// ---------------- projection GEMM (bf16 MFMA, K=512) ----------------
// oT==0: out yab[b][n][128] (a|b packed, bias applied).  oT 1..4: ft[b][c][m] (WHICH=1 raw, WHICH=2 +=, +bias)
template<int WHICH>
__global__ __launch_bounds__(256, 2) void k_gemm(
    const u16* __restrict__ W1, const u16* __restrict__ W2f,
    const u16* __restrict__ xT,
    const float* __restrict__ bb, const float* __restrict__ bc, const float* __restrict__ bd,
    const float* __restrict__ alpha, const float* __restrict__ beta,
    u16* __restrict__ yab, u16* __restrict__ ft)
{
    __shared__ u16 Wt[128][72];
    __shared__ u16 Xt[128][72];
    int t = threadIdx.x, lane = t & 63, w = t >> 6, q = lane >> 4, l15 = lane & 15;
    int nT_ = blockIdx.x, oT = blockIdx.y, batch = blockIdx.z;
    int n0 = nT_ * 128, o0 = oT * 128;
    const u16* Wsrc = (WHICH == 1 || oT == 0) ? (W1 + (size_t)o0 * CDIM)
                                              : (W2f + (size_t)(o0 - 128) * CDIM);
    const u16* xb = xT + ((size_t)batch * NT + n0) * CDIM;
    f32x4 acc[2][8];
    #pragma unroll
    for (int a = 0; a < 2; a++)
        #pragma unroll
        for (int b = 0; b < 8; b++) { f32x4 z = {0.f,0.f,0.f,0.f}; acc[a][b] = z; }

    for (int k0 = 0; k0 < CDIM; k0 += 64) {
        if (k0) __syncthreads();
        int r = t >> 1, h = t & 1;
        #pragma unroll
        for (int u = 0; u < 4; u++) {
            *(uint4*)&Wt[r][h * 32 + u * 8] = *(const uint4*)&Wsrc[(size_t)r * CDIM + k0 + h * 32 + u * 8];
            *(uint4*)&Xt[r][h * 32 + u * 8] = *(const uint4*)&xb[(size_t)r * CDIM + k0 + h * 32 + u * 8];
        }
        __syncthreads();
        if (oT == 0) {
            short8 af[2][2];
            #pragma unroll
            for (int ot = 0; ot < 2; ot++)
                #pragma unroll
                for (int kk = 0; kk < 2; kk++)
                    af[ot][kk] = *(const short8*)&Wt[w * 32 + ot * 16 + l15][kk * 32 + q * 8];
            #pragma unroll
            for (int kk = 0; kk < 2; kk++)
                #pragma unroll
                for (int i = 0; i < 8; i++) {
                    short8 bf = *(const short8*)&Xt[i * 16 + l15][kk * 32 + q * 8];
                    #pragma unroll
                    for (int ot = 0; ot < 2; ot++)
                        acc[ot][i] = __builtin_amdgcn_mfma_f32_16x16x32_bf16(af[ot][kk], bf, acc[ot][i], 0, 0, 0);
                }
        } else {
            short8 wf[2][2];
            #pragma unroll
            for (int ct = 0; ct < 2; ct++)
                #pragma unroll
                for (int kk = 0; kk < 2; kk++)
                    wf[ct][kk] = *(const short8*)&Wt[w * 32 + ct * 16 + l15][kk * 32 + q * 8];
            #pragma unroll
            for (int kk = 0; kk < 2; kk++)
                #pragma unroll
                for (int i = 0; i < 8; i++) {
                    short8 xf = *(const short8*)&Xt[i * 16 + l15][kk * 32 + q * 8];
                    #pragma unroll
                    for (int ct = 0; ct < 2; ct++)
                        acc[ct][i] = __builtin_amdgcn_mfma_f32_16x16x32_bf16(xf, wf[ct][kk], acc[ct][i], 0, 0, 0);
                }
        }
    }

    if (oT == 0) {
        // D[o][n]: regs = 4 consecutive o, col n = l15 -> 8 B store per lane into [n][128]
        #pragma unroll
        for (int ot = 0; ot < 2; ot++)
            #pragma unroll
            for (int i = 0; i < 8; i++) {
                int obase = w * 32 + ot * 16 + q * 4;
                int n = n0 + i * 16 + l15;
                U4 u;
                #pragma unroll
                for (int r = 0; r < 4; r++) {
                    int o = obase + r;
                    float bias = (o < 64) ? bb[o] * LOG2E : bc[o - 64];
                    u.v[r] = f2bf(acc[ot][i][r] + bias);
                }
                *(uint2*)&yab[((size_t)batch * NT + n) * 128 + obase] = u.u2;
            }
    } else {
        float bscale = (WHICH == 2) ? (alpha[0] + beta[0]) : 0.f;
        // D[n][c] (swapped): regs = 4 consecutive m, col c = l15 -> 8 B m-contig store into ft[c][m]
        #pragma unroll
        for (int ct = 0; ct < 2; ct++)
            #pragma unroll
            for (int i = 0; i < 8; i++) {
                int c = (o0 - 128) + w * 32 + ct * 16 + l15;
                int mb = n0 + i * 16 + q * 4;
                u16* dst = &ft[((size_t)batch * CDIM + c) * NT + mb];
                U4 u;
                if (WHICH == 1) {
                    #pragma unroll
                    for (int r = 0; r < 4; r++) u.v[r] = f2bf(acc[ct][i][r]);
                } else {
                    U4 old; old.u2 = *(const uint2*)dst;
                    float bias = bd[c] * bscale;
                    #pragma unroll
                    for (int r = 0; r < 4; r++) u.v[r] = f2bf(acc[ct][i][r] + bf2f(old.v[r]) + bias);
                }
                *(uint2*)dst = u.u2;
            }
    }
}

// ---------------- denominators: denom[dir][b][n] = sum_m exp2(S - SHIFT), m-split x4 ----------------
__global__ __launch_bounds__(256) void k_denom(
    const u16* __restrict__ yab1, const u16* __restrict__ yab2,
    float* __restrict__ denom)
{
    __shared__ u16 a1t[32][72], a2t[32][72];
    __shared__ u16 b1t[128][72], b2t[128][72];
    int t = threadIdx.x, lane = t & 63, w = t >> 6, q = lane >> 4, l15 = lane & 15;
    int x = blockIdx.x & 7;
    int batch = x & 1, mq = x >> 1;
    int n0 = (blockIdx.x >> 3) * 32;
    const u16* y1 = yab1 + (size_t)batch * NT * 128;
    const u16* y2 = yab2 + (size_t)batch * NT * 128;

    *(uint4*)&a1t[t >> 3][(t & 7) * 8] = *(const uint4*)&y1[(size_t)(n0 + (t >> 3)) * 128 + (t & 7) * 8];
    *(uint4*)&a2t[t >> 3][(t & 7) * 8] = *(const uint4*)&y2[(size_t)(n0 + (t >> 3)) * 128 + (t & 7) * 8];
    __syncthreads();

    short8 a1f[2][2], a2f[2][2];
    #pragma unroll
    for (int i = 0; i < 2; i++)
        #pragma unroll
        for (int kk = 0; kk < 2; kk++) {
            a1f[i][kk] = *(const short8*)&a1t[i * 16 + l15][kk * 32 + q * 8];
            a2f[i][kk] = *(const short8*)&a2t[i * 16 + l15][kk * 32 + q * 8];
        }

    float sm[2][2] = {{0.f,0.f},{0.f,0.f}};   // [dir][i]
    for (int mc = mq * 1024; mc < mq * 1024 + 1024; mc += 128) {
        __syncthreads();
        int r = t >> 1, h = t & 1;
        #pragma unroll
        for (int u = 0; u < 4; u++) {
            *(uint4*)&b1t[r][h * 32 + u * 8] = *(const uint4*)&y1[(size_t)(mc + r) * 128 + 64 + h * 32 + u * 8];
            *(uint4*)&b2t[r][h * 32 + u * 8] = *(const uint4*)&y2[(size_t)(mc + r) * 128 + 64 + h * 32 + u * 8];
        }
        __syncthreads();
        #pragma unroll
        for (int mt = 0; mt < 2; mt++) {
            int ml = w * 32 + mt * 16 + l15;
            short8 bA1k0 = *(const short8*)&b1t[ml][q * 8];
            short8 bA1k1 = *(const short8*)&b1t[ml][32 + q * 8];
            short8 bA2k0 = *(const short8*)&b2t[ml][q * 8];
            short8 bA2k1 = *(const short8*)&b2t[ml][32 + q * 8];
            #pragma unroll
            for (int i = 0; i < 2; i++) {
                f32x4 z = {0.f,0.f,0.f,0.f};
                f32x4 s12 = __builtin_amdgcn_mfma_f32_16x16x32_bf16(bA2k0, a1f[i][0], z, 0, 0, 0);
                s12 = __builtin_amdgcn_mfma_f32_16x16x32_bf16(bA2k1, a1f[i][1], s12, 0, 0, 0);
                f32x4 s21 = __builtin_amdgcn_mfma_f32_16x16x32_bf16(bA1k0, a2f[i][0], z, 0, 0, 0);
                s21 = __builtin_amdgcn_mfma_f32_16x16x32_bf16(bA1k1, a2f[i][1], s21, 0, 0, 0);
                #pragma unroll
                for (int r2 = 0; r2 < 4; r2++) {
                    sm[0][i] += fexp2(s12[r2] - SHIFT);
                    sm[1][i] += fexp2(s21[r2] - SHIFT);
                }
            }
        }
    }
    #pragma unroll
    for (int d = 0; d < 2; d++)
        #pragma unroll
        for (int i = 0; i < 2; i++) {
            float v = sm[d][i];
            v += __shfl_xor(v, 16);
            v += __shfl_xor(v, 32);
            if (q == 0)
                atomicAdd(&denom[((size_t)d * NB + batch) * NT + n0 + i * 16 + l15], v);
        }
}

// ---------------- P + apply, m-split x2: out/partial[b][c][n] ----------------
__global__ __launch_bounds__(256, 2) void k_papply(
    const u16* __restrict__ yab1, const u16* __restrict__ yab2,
    const u16* __restrict__ ft, const float* __restrict__ denom,
    float* __restrict__ out, float* __restrict__ partial)
{
    __shared__ u16 a1t[32][72], a2t[32][72];
    __shared__ u16 b1t[128][72], b2t[128][72];
    __shared__ u16 Pt[32][136];
    int t = threadIdx.x, lane = t & 63, w = t >> 6, q = lane >> 4, l15 = lane & 15;
    int x = blockIdx.x & 7;
    int batch = x & 1, mh = (x >> 1) & 1, nlow = x >> 2;
    int n0 = ((blockIdx.x >> 3) * 2 + nlow) * 32;
    const u16* y1 = yab1 + (size_t)batch * NT * 128;
    const u16* y2 = yab2 + (size_t)batch * NT * 128;
    const u16* ftb = ft + (size_t)batch * CDIM * NT;

    *(uint4*)&a1t[t >> 3][(t & 7) * 8] = *(const uint4*)&y1[(size_t)(n0 + (t >> 3)) * 128 + (t & 7) * 8];
    *(uint4*)&a2t[t >> 3][(t & 7) * 8] = *(const uint4*)&y2[(size_t)(n0 + (t >> 3)) * 128 + (t & 7) * 8];
    __syncthreads();

    short8 a1f[2][2], a2f[2][2];
    #pragma unroll
    for (int i = 0; i < 2; i++)
        #pragma unroll
        for (int kk = 0; kk < 2; kk++) {
            a1f[i][kk] = *(const short8*)&a1t[i * 16 + l15][kk * 32 + q * 8];
            a2f[i][kk] = *(const short8*)&a2t[i * 16 + l15][kk * 32 + q * 8];
        }
    float ls12[2], ls21[2];
    #pragma unroll
    for (int i = 0; i < 2; i++) {
        ls12[i] = SHIFT + flog2(denom[(size_t)batch * NT + n0 + i * 16 + l15]);
        ls21[i] = SHIFT + flog2(denom[((size_t)NB + batch) * NT + n0 + i * 16 + l15]);
    }

    f32x4 o[2][8];
    #pragma unroll
    for (int i = 0; i < 2; i++)
        #pragma unroll
        for (int j = 0; j < 8; j++) { f32x4 z = {0.f,0.f,0.f,0.f}; o[i][j] = z; }

    for (int mc = mh * 2048; mc < mh * 2048 + 2048; mc += 128) {
        __syncthreads();
        int r = t >> 1, h = t & 1;
        #pragma unroll
        for (int u = 0; u < 4; u++) {
            *(uint4*)&b1t[r][h * 32 + u * 8] = *(const uint4*)&y1[(size_t)(mc + r) * 128 + 64 + h * 32 + u * 8];
            *(uint4*)&b2t[r][h * 32 + u * 8] = *(const uint4*)&y2[(size_t)(mc + r) * 128 + 64 + h * 32 + u * 8];
        }
        __syncthreads();
        #pragma unroll
        for (int mt = 0; mt < 2; mt++) {
            int ml = w * 32 + mt * 16 + l15;
            short8 bA1k0 = *(const short8*)&b1t[ml][q * 8];
            short8 bA1k1 = *(const short8*)&b1t[ml][32 + q * 8];
            short8 bA2k0 = *(const short8*)&b2t[ml][q * 8];
            short8 bA2k1 = *(const short8*)&b2t[ml][32 + q * 8];
            #pragma unroll
            for (int i = 0; i < 2; i++) {
                f32x4 z = {0.f,0.f,0.f,0.f};
                f32x4 s12 = __builtin_amdgcn_mfma_f32_16x16x32_bf16(bA2k0, a1f[i][0], z, 0, 0, 0);
                s12 = __builtin_amdgcn_mfma_f32_16x16x32_bf16(bA2k1, a1f[i][1], s12, 0, 0, 0);
                f32x4 s21 = __builtin_amdgcn_mfma_f32_16x16x32_bf16(bA1k0, a2f[i][0], z, 0, 0, 0);
                s21 = __builtin_amdgcn_mfma_f32_16x16x32_bf16(bA1k1, a2f[i][1], s21, 0, 0, 0);
                U4 u;
                #pragma unroll
                for (int r2 = 0; r2 < 4; r2++) {
                    float p12 = fexp2(s12[r2] - ls12[i]);
                    float p21 = fexp2(s21[r2] - ls21[i]);
                    u.v[r2] = f2bf(fabsf(p12 - p21));
                }
                // 4 consecutive m per lane -> balanced 8-B LDS write
                *(uint2*)&Pt[i * 16 + l15][w * 32 + mt * 16 + q * 4] = u.u2;
            }
        }
        __syncthreads();
        short8 pa[2][4];
        #pragma unroll
        for (int i = 0; i < 2; i++)
            #pragma unroll
            for (int kk = 0; kk < 4; kk++)
                pa[i][kk] = *(const short8*)&Pt[i * 16 + l15][kk * 32 + q * 8];
        #pragma unroll
        for (int j = 0; j < 8; j++) {
            const u16* fr = ftb + (size_t)(w * 128 + j * 16 + l15) * NT + mc + q * 8;
            short8 fb0 = *(const short8*)(fr);
            short8 fb1 = *(const short8*)(fr + 32);
            short8 fb2 = *(const short8*)(fr + 64);
            short8 fb3 = *(const short8*)(fr + 96);
            #pragma unroll
            for (int i = 0; i < 2; i++) {
                o[i][j] = __builtin_amdgcn_mfma_f32_16x16x32_bf16(pa[i][0], fb0, o[i][j], 0, 0, 0);
                o[i][j] = __builtin_amdgcn_mfma_f32_16x16x32_bf16(pa[i][1], fb1, o[i][j], 0, 0, 0);
                o[i][j] = __builtin_amdgcn_mfma_f32_16x16x32_bf16(pa[i][2], fb2, o[i][j], 0, 0, 0);
                o[i][j] = __builtin_amdgcn_mfma_f32_16x16x32_bf16(pa[i][3], fb3, o[i][j], 0, 0, 0);
            }
        }
    }

    float* dst = mh ? partial : out;
    #pragma unroll
    for (int i = 0; i < 2; i++)
        #pragma unroll
        for (int j = 0; j < 8; j++) {
            int c = w * 128 + j * 16 + l15;
            *(f32x4*)&dst[((size_t)batch * CDIM + c) * NT + n0 + i * 16 + q * 4] = o[i][j];
        }
}

// ---------------- out += partial ----------------
__global__ __launch_bounds__(256) void k_reduce(
    float* __restrict__ out, const float* __restrict__ part, int n4)
{
    int i = blockIdx.x * 256 + threadIdx.x, stride = gridDim.x * 256;
    float4* o4 = (float4*)out;
    const float4* p4 = (const float4*)part;
    for (int j = i; j < n4; j += stride) {
        float4 a = o4[j], b = p4[j];
        o4[j] = make_float4(a.x + b.x, a.y + b.y, a.z + b.z, a.w + b.w);
    }
}

extern "C" void kernel_launch(void* const* d_in, const int* in_sizes, int n_in,
                              void* d_out, int out_size, void* d_ws, size_t ws_size,
                              hipStream_t stream)
{
    const float* x1 = (const float*)d_in[0];
    const float* x2 = (const float*)d_in[1];
    const float* Wb = (const float*)d_in[2];
    const float* bb = (const float*)d_in[3];
    const float* Wc = (const float*)d_in[4];
    const float* bc = (const float*)d_in[5];
    const float* Wd = (const float*)d_in[6];
    const float* bd = (const float*)d_in[7];
    const float* alpha = (const float*)d_in[8];
    const float* beta  = (const float*)d_in[9];
    float* out = (float*)d_out;

    // ws layout (u16 units):
    u16* ws  = (u16*)d_ws;
    u16* x1T = ws;                      // [2][4096][512]  = 4,194,304
    u16* x2T = ws + 4194304;            //                 = 4,194,304
    u16* yab1 = ws + 8388608;           // [2][4096][128]  = 1,048,576
    u16* yab2 = ws + 9437184;           //                 = 1,048,576
    u16* ft   = ws + 10485760;          // [2][512][4096]  = 4,194,304
    u16* W1   = ws + 14680064;          // [640][512]      =   327,680
    u16* W2f  = ws + 15007744;          // [512][512]      =   262,144
    float* denom = (float*)(ws + 15269888);   // [2][2][4096] f32
    float* partial = (float*)ws;        // overlays x1T/x2T after GEMMs (16.8 MB)

    hipMemsetAsync(denom, 0, (size_t)2 * NB * NT * sizeof(float), stream);
    k_convW<<<1152, 256, 0, stream>>>(Wb, Wc, Wd, alpha, beta, W1, W2f);
    k_prep<<<dim3(8, 64, 4), 256, 0, stream>>>(x1, x2, x1T, x2T);
    k_gemm<1><<<dim3(32, 5, 2), 256, 0, stream>>>(W1, W2f, x1T, bb, bc, bd, alpha, beta, yab1, ft);
    k_gemm<2><<<dim3(32, 5, 2), 256, 0, stream>>>(W1, W2f, x2T, bb, bc, bd, alpha, beta, yab2, ft);
    k_denom<<<1024, 256, 0, stream>>>(yab1, yab2, denom);
    k_papply<<<512, 256, 0, stream>>>(yab1, yab2, ft, denom, out, partial);
    k_reduce<<<2048, 256, 0, stream>>>(out, partial, NB * CDIM * NT / 4);
}